// Round 2
// baseline (251.092 us; speedup 1.0000x reference)
//
#include <hip/hip_runtime.h>
#include <hip/hip_bf16.h>

// Problem constants (from reference)
#define RANK   16
#define IN_F   4096
#define OUT_F  4096
#define NBATCH 4
#define SEQLEN 2048
#define NROWS  (NBATCH * SEQLEN)   // 8192
// SCALING = ALPHA/RANK = 16/16 = 1.0 -> omitted

typedef __bf16 bf16x8   __attribute__((ext_vector_type(8)));
typedef float  floatx4  __attribute__((ext_vector_type(4)));
typedef float  floatx16 __attribute__((ext_vector_type(16)));

// Load 8 consecutive f32 (two dwordx4) and round to bf16x8 for MFMA operands.
static __device__ __forceinline__ bf16x8 load_cvt8(const float* __restrict__ p) {
    floatx4 a = *reinterpret_cast<const floatx4*>(p);
    floatx4 b = *reinterpret_cast<const floatx4*>(p + 4);
    bf16x8 r;
    r[0] = (__bf16)a[0]; r[1] = (__bf16)a[1]; r[2] = (__bf16)a[2]; r[3] = (__bf16)a[3];
    r[4] = (__bf16)b[0]; r[5] = (__bf16)b[1]; r[6] = (__bf16)b[2]; r[7] = (__bf16)b[3];
    return r;
}

// ---------------------------------------------------------------------------
// Stage 1: Bx[row, r] = sum_i x[row, i] * B[adapter, r, i]      (row = b*SEQ+n)
// One block per 16-row tile. 4 waves split K=4096 into chunks of 1024
// (32 MFMA 16x16x32 steps each), partials reduced through LDS, result
// stored as bf16 [tile][16 rows][16 r] into workspace.
// A-operand (x):  lane holds A[m=lane&15][k = quad*8 + j]  -> 32B contiguous f32
// B-operand (B):  lane holds B[k][n=lane&15], k = quad*8+j -> 32B contiguous f32
// C layout: col = lane&15 (=r), row = quad*4 + reg
// ---------------------------------------------------------------------------
__global__ __launch_bounds__(256) void
lora_bx_kernel(const float* __restrict__ x, const float* __restrict__ Bw,
               const int* __restrict__ ids, __bf16* __restrict__ bx)
{
    const int tile = blockIdx.x;            // 0..511
    const int row0 = tile * 16;
    const int adapter = ids[row0 / SEQLEN]; // 16-row tiles never cross batches
    const int wave = threadIdx.x >> 6;      // 0..3 -> K chunk of 1024
    const int lane = threadIdx.x & 63;
    const int m    = lane & 15;
    const int quad = lane >> 4;

    const float* xp = x + (size_t)(row0 + m) * IN_F + quad * 8 + wave * 1024;
    const float* bp = Bw + (size_t)adapter * (RANK * IN_F)
                         + (size_t)m * IN_F + quad * 8 + wave * 1024;

    floatx4 acc = {0.f, 0.f, 0.f, 0.f};
#pragma unroll 8
    for (int s = 0; s < 32; ++s) {
        bf16x8 af = load_cvt8(xp + s * 32);
        bf16x8 bf = load_cvt8(bp + s * 32);
        acc = __builtin_amdgcn_mfma_f32_16x16x32_bf16(af, bf, acc, 0, 0, 0);
    }

    __shared__ float red[4][256];
#pragma unroll
    for (int j = 0; j < 4; ++j)
        red[wave][(quad * 4 + j) * 16 + m] = acc[j];   // [C-row][C-col=r]
    __syncthreads();

    const int t = threadIdx.x;              // t = row*16 + r within tile
    float s = (red[0][t] + red[1][t]) + (red[2][t] + red[3][t]);
    bx[tile * 256 + t] = (__bf16)s;
}

// ---------------------------------------------------------------------------
// Stage 2: out[row, o] = sum_r Bx[row, r] * A[adapter, o, r]   (f32 out)
// mfma_f32_32x32x16_bf16: M=32 rows, N=32 out cols, K=16 = RANK exactly.
// Grid: 256 row-tiles x 4 col-chunks; each wave: 8 col-tiles of 32.
// A-operand (Bx): lane holds A[m=lane&31][k=(lane>>5)*8+j] -> bf16 ws, 16B
// B-operand (A):  lane holds B[k][n=lane&31], k=(lane>>5)*8+j; A[o][r] is
//   rank-contiguous f32 -> 32B contiguous, convert to bf16
// C layout: col = lane&31, row = (reg&3) + 8*(reg>>2) + 4*(lane>>5)
// ---------------------------------------------------------------------------
__global__ __launch_bounds__(256) void
lora_out_kernel(const __bf16* __restrict__ bx, const float* __restrict__ Aw,
                const int* __restrict__ ids, float* __restrict__ out)
{
    const int rt    = blockIdx.x >> 2;      // 0..255, 32-row tiles
    const int chunk = blockIdx.x & 3;       // 0..3, 1024-col chunks
    const int row0  = rt * 32;
    const int adapter = ids[row0 / SEQLEN]; // 32 | 2048, no batch crossing
    const int wave = threadIdx.x >> 6;
    const int lane = threadIdx.x & 63;
    const int n    = lane & 31;
    const int half = lane >> 5;

    const bf16x8 a_bx = *reinterpret_cast<const bf16x8*>(
        bx + rt * 512 + n * 16 + half * 8);

    const float* ap = Aw + (size_t)adapter * (OUT_F * RANK) + half * 8;
    const int colbase = chunk * 1024 + wave * 256;

#pragma unroll
    for (int tcol = 0; tcol < 8; ++tcol) {
        const int col0 = colbase + tcol * 32;
        bf16x8 bfrag = load_cvt8(ap + (size_t)(col0 + n) * RANK);
        floatx16 c;
#pragma unroll
        for (int i = 0; i < 16; ++i) c[i] = 0.f;
        c = __builtin_amdgcn_mfma_f32_32x32x16_bf16(a_bx, bfrag, c, 0, 0, 0);
#pragma unroll
        for (int reg = 0; reg < 16; ++reg) {
            const int r = (reg & 3) + 8 * (reg >> 2) + 4 * half;
            out[(size_t)(row0 + r) * OUT_F + col0 + n] = c[reg];
        }
    }
}

extern "C" void kernel_launch(void* const* d_in, const int* in_sizes, int n_in,
                              void* d_out, int out_size, void* d_ws, size_t ws_size,
                              hipStream_t stream) {
    const float* x   = (const float*)d_in[0]; // [4, 2048, 4096] f32
    const float* Aw  = (const float*)d_in[1]; // [8, 4096, 16]   f32
    const float* Bw  = (const float*)d_in[2]; // [8, 16, 4096]   f32
    const int*   ids = (const int*)d_in[3];   // [4] int32
    float* out = (float*)d_out;               // [4, 2048, 4096] f32
    __bf16* bx = (__bf16*)d_ws;               // 8192*16 bf16 = 256 KB scratch

    lora_bx_kernel<<<dim3(NROWS / 16), dim3(256), 0, stream>>>(x, Bw, ids, bx);
    lora_out_kernel<<<dim3((NROWS / 32) * 4), dim3(256), 0, stream>>>(bx, Aw, ids, out);
}